// Round 17
// baseline (541.653 us; speedup 1.0000x reference)
//
#include <hip/hip_runtime.h>

typedef __attribute__((ext_vector_type(4))) float f32x4;
typedef __attribute__((ext_vector_type(8))) short s16x8;

#define MFMA16(a, b, c) __builtin_amdgcn_mfma_f32_16x16x32_bf16((a), (b), (c), 0, 0, 0)

__device__ __forceinline__ float hsig(float x) {
    return fminf(fmaxf(0.2f * x + 0.5f, 0.0f), 1.0f);
}

__device__ __forceinline__ unsigned short bf16rne(float v) {
    unsigned u = __float_as_uint(v);
    u += 0x7FFFu + ((u >> 16) & 1u);
    return (unsigned short)(u >> 16);
}
__device__ __forceinline__ void split2(float v, unsigned short& h, unsigned short& l) {
    h = bf16rne(v);
    float hv = __uint_as_float((unsigned)h << 16);
    l = bf16rne(v - hv);
}

// ---- weight prep: MFMA A-fragment order, GATE-INTERLEAVED rows, hi/lo split ----
// Bw layout: [ks][ hi: nfrag(16) x lane(64) x 8 | lo: same ]  (16384 ushorts per ks)
// Row n = output channel in interleaved order c' = 4*feature + gate.
template<int KHW, int CX, int NS>
__global__ __launch_bounds__(256)
void prep_w(const float* __restrict__ Kw, const float* __restrict__ Rw,
            unsigned short* __restrict__ Bw)
{
    int gid = blockIdx.x * 256 + threadIdx.x;
    if (gid >= NS * 1024) return;
    int lane  = gid & 63;
    int nfrag = (gid >> 6) & 15;
    int ks    = gid >> 10;
    int n   = nfrag * 16 + (lane & 15);       // interleaved channel c'
    int src = (n & 3) * 64 + (n >> 2);        // original col: gate*64 + feature
    int kl  = (lane >> 4) * 8;
    constexpr int KX = KHW * CX;
    s16x8 vh, vl;
#pragma unroll
    for (int j = 0; j < 8; ++j) {
        int kg = ks * 32 + kl + j;
        float w = (kg < KX) ? Kw[(long)kg * 256 + src]
                            : Rw[(long)(kg - KX) * 256 + src];
        unsigned short h, l;
        split2(w, h, l);
        vh[j] = (short)h;
        vl[j] = (short)l;
    }
    unsigned short* o = Bw + (long)ks * 16384 + nfrag * 512 + lane * 8;
    *(s16x8*)o = vh;
    *(s16x8*)(o + 8192) = vl;
}

// ---- stage zero-padded tile as SINGLE bf16 plane (RNE), chunk-major ----
template<int C, int TS, int PAD, int CST>
__device__ __forceinline__ void stage_bf16(const float* __restrict__ gp,
                                           unsigned short* __restrict__ dst,
                                           int ty0, int tx0, int tid)
{
    constexpr int CH = C / 8;
    constexpr int NP = TS * TS;
    for (int i = tid; i < NP * CH; i += 512) {
        int ch = i % CH;
        int p  = i / CH;
        int py = p / TS, px = p % TS;
        int iy = ty0 + py - PAD, ix = tx0 + px - PAD;
        s16x8 vb;
        if (iy >= 0 && iy < 64 && ix >= 0 && ix < 64) {
            const float* s = gp + ((long)(iy * 64 + ix)) * C + ch * 8;
            f32x4 a = *(const f32x4*)s;
            f32x4 b = *(const f32x4*)(s + 4);
#pragma unroll
            for (int j = 0; j < 4; ++j) {
                vb[j]     = (short)bf16rne(a[j]);
                vb[4 + j] = (short)bf16rne(b[j]);
            }
        } else {
#pragma unroll
            for (int j = 0; j < 8; ++j) vb[j] = 0;
        }
        *(s16x8*)(dst + ch * CST + p * 8) = vb;
    }
}

// ---- ConvLSTM step body: swapped-operand MFMA (z^T = W * X), 2-pass ----
// 8 waves; wave w owns channels [32w,32w+32) x ALL 64 pixels, full K.
// r17: explicit 1-deep W prefetch (bq strides 16384 uniformly across the
// WHOLE K range, x-phase and h-phase alike) + setprio REMOVED (per-KSTEP
// setprio bracket fenced the scheduler; r16 measured dispatch = MFMA-floor
// + L2-B-time EXACTLY, i.e. zero load/compute overlap). The "is last kstep"
// prefetch guard is a compile-time constant (folded in the unrolled nests).
template<int KW, int CX, int TS, int NS, int XS>
__device__ __forceinline__ void lstm_body(
    unsigned short* __restrict__ smem,
    float* __restrict__ hplane,       // [64][65] f32, dedicated
    const float* __restrict__ xin, long xbstride,
    const float* __restrict__ hin,
    const unsigned short* __restrict__ Bg,
    const float* __restrict__ bias,
    float* __restrict__ c_buf,        // thread-keyed coalesced (internal)
    float* __restrict__ h_out,
    float* __restrict__ y_out, long ybstride,
    int b)
{
    constexpr int PAD = KW / 2;
    constexpr int NP  = TS * TS;
    constexpr int CHX = CX / 8;
    constexpr int CST = NP * 8;              // chunk stride (ushorts)
    constexpr int XPLANE = CHX * CST;

    unsigned short* sx = smem;               // x plane (CHX chunks)
    unsigned short* sh = sx + XPLANE;        // h plane (8 chunks)

    const int tid  = threadIdx.x;
    const int lane = tid & 63, wid = tid >> 6;
    const int ty0 = blockIdx.y * 8, tx0 = blockIdx.x * 8;

    // W fragment stream: wave w owns nfrags {2w, 2w+1} = channels [32w, 32w+32)
    const unsigned short* bq = Bg + (2 * wid) * 512 + lane * 8;

    // prologue W load: L2 latency hides under staging + barrier
    s16x8 Wc0 = *(const s16x8*)(bq);
    s16x8 Wc1 = *(const s16x8*)(bq + 512);
    s16x8 Wc2 = *(const s16x8*)(bq + 8192);
    s16x8 Wc3 = *(const s16x8*)(bq + 8192 + 512);
    s16x8 Wn0, Wn1, Wn2, Wn3;

    stage_bf16<CX, TS, PAD, CST>(xin + (long)b * xbstride, sx, ty0, tx0, tid);
    stage_bf16<64, TS, PAD, CST>(hin + (long)b * 4096 * 64, sh, ty0, tx0, tid);
    __syncthreads();

    f32x4 acc[2][4];   // [cf][pf]
#pragma unroll
    for (int cf = 0; cf < 2; ++cf)
#pragma unroll
        for (int pf = 0; pf < 4; ++pf)
#pragma unroll
            for (int q = 0; q < 4; ++q) acc[cf][pf][q] = 0.0f;

    // thread-const X offsets (ushort units). pixel p = pf*16 + (lane&15)
    const int pb  = lane & 15;
    const int kq  = (lane >> 4) * CST;
    const int av0 = (((pb      >> 3) * TS) + (pb      & 7)) * 8 + kq;
    const int av1 = ((((pb+16) >> 3) * TS) + ((pb+16) & 7)) * 8 + kq;
    const int av2 = ((((pb+32) >> 3) * TS) + ((pb+32) & 7)) * 8 + kq;
    const int av3 = ((((pb+48) >> 3) * TS) + ((pb+48) & 7)) * 8 + kq;

    // one k-step: prefetch NEXT W (4x16B from L2), X from LDS (4x16B),
    // 16 MFMA with CURRENT W, rotate. PF=0 only on the final k-step.
#define KSTEP(PX, SO, PF)                                                 \
    {                                                                     \
        if (PF) {                                                         \
            Wn0 = *(const s16x8*)(bq + 16384);                            \
            Wn1 = *(const s16x8*)(bq + 16384 + 512);                      \
            Wn2 = *(const s16x8*)(bq + 16384 + 8192);                     \
            Wn3 = *(const s16x8*)(bq + 16384 + 8192 + 512);               \
        }                                                                 \
        s16x8 X0 = *(const s16x8*)((PX) + (SO) + av0);                    \
        s16x8 X1 = *(const s16x8*)((PX) + (SO) + av1);                    \
        s16x8 X2 = *(const s16x8*)((PX) + (SO) + av2);                    \
        s16x8 X3 = *(const s16x8*)((PX) + (SO) + av3);                    \
        acc[0][0] = MFMA16(Wc0, X0, acc[0][0]);                           \
        acc[1][0] = MFMA16(Wc1, X0, acc[1][0]);                           \
        acc[0][1] = MFMA16(Wc0, X1, acc[0][1]);                           \
        acc[1][1] = MFMA16(Wc1, X1, acc[1][1]);                           \
        acc[0][2] = MFMA16(Wc0, X2, acc[0][2]);                           \
        acc[1][2] = MFMA16(Wc1, X2, acc[1][2]);                           \
        acc[0][3] = MFMA16(Wc0, X3, acc[0][3]);                           \
        acc[1][3] = MFMA16(Wc1, X3, acc[1][3]);                           \
        acc[0][0] = MFMA16(Wc2, X0, acc[0][0]);                           \
        acc[1][0] = MFMA16(Wc3, X0, acc[1][0]);                           \
        acc[0][1] = MFMA16(Wc2, X1, acc[0][1]);                           \
        acc[1][1] = MFMA16(Wc3, X1, acc[1][1]);                           \
        acc[0][2] = MFMA16(Wc2, X2, acc[0][2]);                           \
        acc[1][2] = MFMA16(Wc3, X2, acc[1][2]);                           \
        acc[0][3] = MFMA16(Wc2, X3, acc[0][3]);                           \
        acc[1][3] = MFMA16(Wc3, X3, acc[1][3]);                           \
        if (PF) { Wc0 = Wn0; Wc1 = Wn1; Wc2 = Wn2; Wc3 = Wn3; }           \
        bq += 16384;                                                      \
    }

    // ---- x-phase (k-step order matches prep_w; h-phase always follows
    //      so every x-phase k-step prefetches) ----
    if (CX == 32) {
#pragma unroll 1
        for (int kh = 0; kh < KW; ++kh) {
#pragma unroll
            for (int kw = 0; kw < KW; ++kw) {
                KSTEP(sx, (kh * TS + kw) * 8, 1);
            }
        }
    } else {
#pragma unroll 1
        for (int kh = 0; kh < KW; ++kh) {
#pragma unroll
            for (int kw = 0; kw < KW; ++kw) {
#pragma unroll
                for (int c2 = 0; c2 < 2; ++c2) {
                    KSTEP(sx, c2 * 4 * CST + (kh * TS + kw) * 8, 1);
                }
            }
        }
    }
    // ---- h-phase (C=64); last k-step (kh=kw=KW-1, c2=1) skips prefetch ----
#pragma unroll 1
    for (int kh = 0; kh < KW; ++kh) {
#pragma unroll
        for (int kw = 0; kw < KW; ++kw) {
#pragma unroll
            for (int c2 = 0; c2 < 2; ++c2) {
                KSTEP(sh, c2 * 4 * CST + (kh * TS + kw) * 8,
                      !(kh == KW - 1 && kw == KW - 1 && c2 == 1));
            }
        }
    }
#undef KSTEP

    // ---- per-lane gates -> c update (thread-keyed coalesced) + hn to LDS ----
    // Lane holds gates q={i,f,g,o} of feature f = wid*8 + cf*4 + (lane>>4)
    // at pixel p = pf*16 + (lane&15).
    const int pxb  = lane & 15;
    const int fq   = lane >> 4;
    const int tile = blockIdx.y * 8 + blockIdx.x;
    const long cb0 = (((long)b * 64 + tile) * 8) * 512 + tid;
#pragma unroll
    for (int cf = 0; cf < 2; ++cf) {
        const int f = wid * 8 + cf * 4 + fq;
        const float bi  = bias[f];
        const float bfr = bias[64 + f];
        const float bg  = bias[128 + f];
        const float bo  = bias[192 + f];
#pragma unroll
        for (int pf = 0; pf < 4; ++pf) {
            int p   = pf * 16 + pxb;
            long oc = cb0 + (long)(cf * 4 + pf) * 512;   // 512 threads x 4B
            float zi = acc[cf][pf][0] + bi;
            float zf = acc[cf][pf][1] + bfr;
            float zg = acc[cf][pf][2] + bg;
            float zo = acc[cf][pf][3] + bo;
            float cv = c_buf[oc];
            float cn = hsig(zf) * cv + hsig(zi) * tanhf(zg);
            c_buf[oc] = cn;
            hplane[p * 65 + f] = hsig(zo) * tanhf(cn);
        }
    }
    __syncthreads();

    // ---- coalesced h/y write: lane = feature, 256B-contiguous stores ----
    const int f = tid & 63;
#pragma unroll
    for (int j = 0; j < 8; ++j) {
        int p  = (tid >> 6) + j * 8;             // 0..63
        int yy = ty0 + (p >> 3), xx = tx0 + (p & 7);
        int gp = yy * 64 + xx;
        float hn = hplane[p * 65 + f];
        long o = ((long)(b * 64 + yy) * 64 + xx) * 64 + f;
        h_out[o] = hn;
        y_out[(long)b * ybstride + (long)gp * 64 + f] = fmaxf(hn, 0.0f);
    }
}

// ---- fused dual-layer launch: z<4 -> layer1 step t, z>=4 -> layer2 step t-1 ----
// LDS 44.3 KB/block, regs ~72 arch + 32 acc <= 128 -> 2 blocks/CU co-resident.
__global__ __launch_bounds__(512, 2)
void lstm_fused(
    const float* __restrict__ x1, const float* __restrict__ h1in,
    const unsigned short* __restrict__ B1g, const float* __restrict__ bias1,
    float* __restrict__ c1, float* __restrict__ h1out, float* __restrict__ y1out,
    const float* __restrict__ x2, const float* __restrict__ h2in,
    const unsigned short* __restrict__ B2g, const float* __restrict__ bias2,
    float* __restrict__ c2, float* __restrict__ h2out, float* __restrict__ y2out,
    int mode)
{
    // L1: (4+8)*1152 = 13824 u16; L2: (8+8)*800 = 12800 u16 -> max 13824
    __shared__ __align__(16) unsigned short smem[13824];
    __shared__ __align__(16) float hplane[64 * 65];
    const int z = blockIdx.z;
    const int b = z & 3;
    const bool doL2 = (mode == 1) || (z >= 4);
    if (!doL2) {
        lstm_body<5, 32, 12, 75, 25>(smem, hplane, x1, (long)8 * 4096 * 32, h1in,
                                     B1g, bias1, c1, h1out,
                                     y1out, (long)8 * 4096 * 64, b);
    } else {
        lstm_body<3, 64, 10, 36, 18>(smem, hplane, x2, (long)8 * 4096 * 64, h2in,
                                     B2g, bias2, c2, h2out,
                                     y2out, (long)8 * 4096 * 64, b);
    }
}

extern "C" void kernel_launch(void* const* d_in, const int* in_sizes, int n_in,
                              void* d_out, int out_size, void* d_ws, size_t ws_size,
                              hipStream_t stream)
{
    const float* x  = (const float*)d_in[0];
    const float* K1 = (const float*)d_in[1];
    const float* R1 = (const float*)d_in[2];
    const float* b1 = (const float*)d_in[3];
    const float* K2 = (const float*)d_in[4];
    const float* R2 = (const float*)d_in[5];
    const float* b2 = (const float*)d_in[6];
    float* out = (float*)d_out;

    const long HW   = 4096;
    const long SZ_S = HW * 64 * 4;      // 1,048,576 floats per [B,H,W,64]
    const long SZ_Y = SZ_S * 8;

    float* ws  = (float*)d_ws;
    float* y1  = ws;                    // 8,388,608 f32 ([B][T][HW][64])
    float* h1a = y1 + SZ_Y;
    float* h1b = h1a + SZ_S;
    float* h2a = h1b + SZ_S;
    float* h2b = h2a + SZ_S;
    float* c1  = h2b + SZ_S;
    float* c2  = c1 + SZ_S;
    unsigned short* B1 = (unsigned short*)(c2 + SZ_S);   // 75*16384 ushorts
    unsigned short* B2 = B1 + (long)75 * 16384;          // 36*16384 ushorts

    // weight prep
    prep_w<25, 32, 75><<<300, 256, 0, stream>>>(K1, R1, B1);
    prep_w<9,  64, 36><<<144, 256, 0, stream>>>(K2, R2, B2);

    hipMemsetAsync(h1a, 0, (size_t)SZ_S * sizeof(float), stream);
    hipMemsetAsync(c1,  0, (size_t)SZ_S * sizeof(float), stream);
    hipMemsetAsync(h2a, 0, (size_t)SZ_S * sizeof(float), stream);
    hipMemsetAsync(c2,  0, (size_t)SZ_S * sizeof(float), stream);

    float* hp1 = h1a; float* hn1 = h1b;
    float* hp2 = h2a; float* hn2 = h2b;

    for (int t = 0; t <= 8; ++t) {
        const int mode = (t == 0) ? 0 : (t == 8) ? 1 : 2;
        const int t1  = (t <= 7) ? t : 7;       // L1 timestep (unused at t=8)
        const int tm1 = (t >= 1) ? t - 1 : 0;   // L2 timestep (unused at t=0)
        dim3 grid(8, 8, mode == 2 ? 8 : 4);
        lstm_fused<<<grid, 512, 0, stream>>>(
            x  + (long)t1 * HW * 32,  hp1, B1, b1, c1, hn1,
            y1 + (long)t1 * HW * 64,
            y1 + (long)tm1 * HW * 64, hp2, B2, b2, c2, hn2,
            out + (long)tm1 * HW * 64,
            mode);
        if (mode != 1) { float* tmp = hp1; hp1 = hn1; hn1 = tmp; }
        if (mode != 0) { float* tmp = hp2; hp2 = hn2; hn2 = tmp; }
    }
}

// Round 18
// 346.914 us; speedup vs baseline: 1.5613x; 1.5613x over previous
//
#include <hip/hip_runtime.h>

typedef __attribute__((ext_vector_type(4))) float f32x4;
typedef __attribute__((ext_vector_type(8))) short s16x8;

#define MFMA16(a, b, c) __builtin_amdgcn_mfma_f32_16x16x32_bf16((a), (b), (c), 0, 0, 0)

__device__ __forceinline__ float hsig(float x) {
    return fminf(fmaxf(0.2f * x + 0.5f, 0.0f), 1.0f);
}

__device__ __forceinline__ unsigned short bf16rne(float v) {
    unsigned u = __float_as_uint(v);
    u += 0x7FFFu + ((u >> 16) & 1u);
    return (unsigned short)(u >> 16);
}

// ---- weight prep: MFMA A-fragment order, GATE-INTERLEAVED rows, bf16 RNE ----
// Bw layout: [ks][ nfrag(16) x lane(64) x 8 ]  (8192 ushorts per ks, hi only)
// Row n = output channel in interleaved order c' = 4*feature + gate.
template<int KHW, int CX, int NS>
__global__ __launch_bounds__(256)
void prep_w(const float* __restrict__ Kw, const float* __restrict__ Rw,
            unsigned short* __restrict__ Bw)
{
    int gid = blockIdx.x * 256 + threadIdx.x;
    if (gid >= NS * 1024) return;
    int lane  = gid & 63;
    int nfrag = (gid >> 6) & 15;
    int ks    = gid >> 10;
    int n   = nfrag * 16 + (lane & 15);       // interleaved channel c'
    int src = (n & 3) * 64 + (n >> 2);        // original col: gate*64 + feature
    int kl  = (lane >> 4) * 8;
    constexpr int KX = KHW * CX;
    s16x8 vh;
#pragma unroll
    for (int j = 0; j < 8; ++j) {
        int kg = ks * 32 + kl + j;
        float w = (kg < KX) ? Kw[(long)kg * 256 + src]
                            : Rw[(long)(kg - KX) * 256 + src];
        vh[j] = (short)bf16rne(w);
    }
    unsigned short* o = Bw + (long)ks * 8192 + nfrag * 512 + lane * 8;
    *(s16x8*)o = vh;
}

// ---- stage zero-padded tile as SINGLE bf16 plane (RNE), chunk-major ----
template<int C, int TS, int PAD, int CST>
__device__ __forceinline__ void stage_bf16(const float* __restrict__ gp,
                                           unsigned short* __restrict__ dst,
                                           int ty0, int tx0, int tid)
{
    constexpr int CH = C / 8;
    constexpr int NP = TS * TS;
    for (int i = tid; i < NP * CH; i += 512) {
        int ch = i % CH;
        int p  = i / CH;
        int py = p / TS, px = p % TS;
        int iy = ty0 + py - PAD, ix = tx0 + px - PAD;
        s16x8 vb;
        if (iy >= 0 && iy < 64 && ix >= 0 && ix < 64) {
            const float* s = gp + ((long)(iy * 64 + ix)) * C + ch * 8;
            f32x4 a = *(const f32x4*)s;
            f32x4 b = *(const f32x4*)(s + 4);
#pragma unroll
            for (int j = 0; j < 4; ++j) {
                vb[j]     = (short)bf16rne(a[j]);
                vb[4 + j] = (short)bf16rne(b[j]);
            }
        } else {
#pragma unroll
            for (int j = 0; j < 8; ++j) vb[j] = 0;
        }
        *(s16x8*)(dst + ch * CST + p * 8) = vb;
    }
}

// ---- ConvLSTM step body: swapped-operand MFMA (z^T = W * X), SINGLE pass ----
// r18: W rounded once to bf16 (like X since r16; absmax was pinned at 2^-9 by
// the bf16 recurrence, not operand precision). 8 MFMA/k-step (floor 14.4 us),
// B L2 traffic halves. Structure otherwise IDENTICAL to r16 (the 469 us best):
// JIT loads inside KSTEP, setprio bracket, compile-time loop nests.
template<int KW, int CX, int TS, int NS, int XS>
__device__ __forceinline__ void lstm_body(
    unsigned short* __restrict__ smem,
    float* __restrict__ hplane,       // [64][65] f32, dedicated
    const float* __restrict__ xin, long xbstride,
    const float* __restrict__ hin,
    const unsigned short* __restrict__ Bg,
    const float* __restrict__ bias,
    float* __restrict__ c_buf,        // thread-keyed coalesced (internal)
    float* __restrict__ h_out,
    float* __restrict__ y_out, long ybstride,
    int b)
{
    constexpr int PAD = KW / 2;
    constexpr int NP  = TS * TS;
    constexpr int CHX = CX / 8;
    constexpr int CST = NP * 8;              // chunk stride (ushorts)
    constexpr int XPLANE = CHX * CST;

    unsigned short* sx = smem;               // x plane (CHX chunks)
    unsigned short* sh = sx + XPLANE;        // h plane (8 chunks)

    const int tid  = threadIdx.x;
    const int lane = tid & 63, wid = tid >> 6;
    const int ty0 = blockIdx.y * 8, tx0 = blockIdx.x * 8;

    // W fragment stream: wave w owns nfrags {2w, 2w+1} = channels [32w, 32w+32)
    const unsigned short* bq = Bg + (2 * wid) * 512 + lane * 8;

    stage_bf16<CX, TS, PAD, CST>(xin + (long)b * xbstride, sx, ty0, tx0, tid);
    stage_bf16<64, TS, PAD, CST>(hin + (long)b * 4096 * 64, sh, ty0, tx0, tid);
    __syncthreads();

    f32x4 acc[2][4];   // [cf][pf]
#pragma unroll
    for (int cf = 0; cf < 2; ++cf)
#pragma unroll
        for (int pf = 0; pf < 4; ++pf)
#pragma unroll
            for (int q = 0; q < 4; ++q) acc[cf][pf][q] = 0.0f;

    // thread-const X offsets (ushort units). pixel p = pf*16 + (lane&15)
    const int pb  = lane & 15;
    const int kq  = (lane >> 4) * CST;
    const int av0 = (((pb      >> 3) * TS) + (pb      & 7)) * 8 + kq;
    const int av1 = ((((pb+16) >> 3) * TS) + ((pb+16) & 7)) * 8 + kq;
    const int av2 = ((((pb+32) >> 3) * TS) + ((pb+32) & 7)) * 8 + kq;
    const int av3 = ((((pb+48) >> 3) * TS) + ((pb+48) & 7)) * 8 + kq;

    // one k-step: W from L2 (2x16B), X from LDS (4x16B), 8 MFMA.
#define KSTEP(PX, SO)                                                     \
    {                                                                     \
        s16x8 W0 = *(const s16x8*)(bq);                                   \
        s16x8 W1 = *(const s16x8*)(bq + 512);                             \
        s16x8 X0 = *(const s16x8*)((PX) + (SO) + av0);                    \
        s16x8 X1 = *(const s16x8*)((PX) + (SO) + av1);                    \
        s16x8 X2 = *(const s16x8*)((PX) + (SO) + av2);                    \
        s16x8 X3 = *(const s16x8*)((PX) + (SO) + av3);                    \
        __builtin_amdgcn_s_setprio(1);                                    \
        acc[0][0] = MFMA16(W0, X0, acc[0][0]);                            \
        acc[1][0] = MFMA16(W1, X0, acc[1][0]);                            \
        acc[0][1] = MFMA16(W0, X1, acc[0][1]);                            \
        acc[1][1] = MFMA16(W1, X1, acc[1][1]);                            \
        acc[0][2] = MFMA16(W0, X2, acc[0][2]);                            \
        acc[1][2] = MFMA16(W1, X2, acc[1][2]);                            \
        acc[0][3] = MFMA16(W0, X3, acc[0][3]);                            \
        acc[1][3] = MFMA16(W1, X3, acc[1][3]);                            \
        __builtin_amdgcn_s_setprio(0);                                    \
        bq += 8192;                                                       \
    }

    // ---- x-phase (k-step order matches prep_w) ----
    if (CX == 32) {
#pragma unroll 1
        for (int kh = 0; kh < KW; ++kh) {
#pragma unroll
            for (int kw = 0; kw < KW; ++kw) {
                KSTEP(sx, (kh * TS + kw) * 8);
            }
        }
    } else {
#pragma unroll 1
        for (int kh = 0; kh < KW; ++kh) {
#pragma unroll
            for (int kw = 0; kw < KW; ++kw) {
#pragma unroll
                for (int c2 = 0; c2 < 2; ++c2) {
                    KSTEP(sx, c2 * 4 * CST + (kh * TS + kw) * 8);
                }
            }
        }
    }
    // ---- h-phase (C=64) ----
#pragma unroll 1
    for (int kh = 0; kh < KW; ++kh) {
#pragma unroll
        for (int kw = 0; kw < KW; ++kw) {
#pragma unroll
            for (int c2 = 0; c2 < 2; ++c2) {
                KSTEP(sh, c2 * 4 * CST + (kh * TS + kw) * 8);
            }
        }
    }
#undef KSTEP

    // ---- per-lane gates -> c update (thread-keyed coalesced) + hn to LDS ----
    // Lane holds gates q={i,f,g,o} of feature f = wid*8 + cf*4 + (lane>>4)
    // at pixel p = pf*16 + (lane&15).
    const int pxb  = lane & 15;
    const int fq   = lane >> 4;
    const int tile = blockIdx.y * 8 + blockIdx.x;
    const long cb0 = (((long)b * 64 + tile) * 8) * 512 + tid;
#pragma unroll
    for (int cf = 0; cf < 2; ++cf) {
        const int f = wid * 8 + cf * 4 + fq;
        const float bi  = bias[f];
        const float bfr = bias[64 + f];
        const float bg  = bias[128 + f];
        const float bo  = bias[192 + f];
#pragma unroll
        for (int pf = 0; pf < 4; ++pf) {
            int p   = pf * 16 + pxb;
            long oc = cb0 + (long)(cf * 4 + pf) * 512;   // 512 threads x 4B
            float zi = acc[cf][pf][0] + bi;
            float zf = acc[cf][pf][1] + bfr;
            float zg = acc[cf][pf][2] + bg;
            float zo = acc[cf][pf][3] + bo;
            float cv = c_buf[oc];
            float cn = hsig(zf) * cv + hsig(zi) * tanhf(zg);
            c_buf[oc] = cn;
            hplane[p * 65 + f] = hsig(zo) * tanhf(cn);
        }
    }
    __syncthreads();

    // ---- coalesced h/y write: lane = feature, 256B-contiguous stores ----
    const int f = tid & 63;
#pragma unroll
    for (int j = 0; j < 8; ++j) {
        int p  = (tid >> 6) + j * 8;             // 0..63
        int yy = ty0 + (p >> 3), xx = tx0 + (p & 7);
        int gp = yy * 64 + xx;
        float hn = hplane[p * 65 + f];
        long o = ((long)(b * 64 + yy) * 64 + xx) * 64 + f;
        h_out[o] = hn;
        y_out[(long)b * ybstride + (long)gp * 64 + f] = fmaxf(hn, 0.0f);
    }
}

// ---- fused dual-layer launch: z<4 -> layer1 step t, z>=4 -> layer2 step t-1 ----
// LDS 44.3 KB/block, regs ~40 arch + 32 acc <= 128 -> 2 blocks/CU co-resident.
__global__ __launch_bounds__(512, 2)
void lstm_fused(
    const float* __restrict__ x1, const float* __restrict__ h1in,
    const unsigned short* __restrict__ B1g, const float* __restrict__ bias1,
    float* __restrict__ c1, float* __restrict__ h1out, float* __restrict__ y1out,
    const float* __restrict__ x2, const float* __restrict__ h2in,
    const unsigned short* __restrict__ B2g, const float* __restrict__ bias2,
    float* __restrict__ c2, float* __restrict__ h2out, float* __restrict__ y2out,
    int mode)
{
    // L1: (4+8)*1152 = 13824 u16; L2: (8+8)*800 = 12800 u16 -> max 13824
    __shared__ __align__(16) unsigned short smem[13824];
    __shared__ __align__(16) float hplane[64 * 65];
    const int z = blockIdx.z;
    const int b = z & 3;
    const bool doL2 = (mode == 1) || (z >= 4);
    if (!doL2) {
        lstm_body<5, 32, 12, 75, 25>(smem, hplane, x1, (long)8 * 4096 * 32, h1in,
                                     B1g, bias1, c1, h1out,
                                     y1out, (long)8 * 4096 * 64, b);
    } else {
        lstm_body<3, 64, 10, 36, 18>(smem, hplane, x2, (long)8 * 4096 * 64, h2in,
                                     B2g, bias2, c2, h2out,
                                     y2out, (long)8 * 4096 * 64, b);
    }
}

extern "C" void kernel_launch(void* const* d_in, const int* in_sizes, int n_in,
                              void* d_out, int out_size, void* d_ws, size_t ws_size,
                              hipStream_t stream)
{
    const float* x  = (const float*)d_in[0];
    const float* K1 = (const float*)d_in[1];
    const float* R1 = (const float*)d_in[2];
    const float* b1 = (const float*)d_in[3];
    const float* K2 = (const float*)d_in[4];
    const float* R2 = (const float*)d_in[5];
    const float* b2 = (const float*)d_in[6];
    float* out = (float*)d_out;

    const long HW   = 4096;
    const long SZ_S = HW * 64 * 4;      // 1,048,576 floats per [B,H,W,64]
    const long SZ_Y = SZ_S * 8;

    float* ws  = (float*)d_ws;
    float* y1  = ws;                    // 8,388,608 f32 ([B][T][HW][64])
    float* h1a = y1 + SZ_Y;
    float* h1b = h1a + SZ_S;
    float* h2a = h1b + SZ_S;
    float* h2b = h2a + SZ_S;
    float* c1  = h2b + SZ_S;
    float* c2  = c1 + SZ_S;
    unsigned short* B1 = (unsigned short*)(c2 + SZ_S);   // 75*8192 ushorts
    unsigned short* B2 = B1 + (long)75 * 8192;           // 36*8192 ushorts

    // weight prep
    prep_w<25, 32, 75><<<300, 256, 0, stream>>>(K1, R1, B1);
    prep_w<9,  64, 36><<<144, 256, 0, stream>>>(K2, R2, B2);

    hipMemsetAsync(h1a, 0, (size_t)SZ_S * sizeof(float), stream);
    hipMemsetAsync(c1,  0, (size_t)SZ_S * sizeof(float), stream);
    hipMemsetAsync(h2a, 0, (size_t)SZ_S * sizeof(float), stream);
    hipMemsetAsync(c2,  0, (size_t)SZ_S * sizeof(float), stream);

    float* hp1 = h1a; float* hn1 = h1b;
    float* hp2 = h2a; float* hn2 = h2b;

    for (int t = 0; t <= 8; ++t) {
        const int mode = (t == 0) ? 0 : (t == 8) ? 1 : 2;
        const int t1  = (t <= 7) ? t : 7;       // L1 timestep (unused at t=8)
        const int tm1 = (t >= 1) ? t - 1 : 0;   // L2 timestep (unused at t=0)
        dim3 grid(8, 8, mode == 2 ? 8 : 4);
        lstm_fused<<<grid, 512, 0, stream>>>(
            x  + (long)t1 * HW * 32,  hp1, B1, b1, c1, hn1,
            y1 + (long)t1 * HW * 64,
            y1 + (long)tm1 * HW * 64, hp2, B2, b2, c2, hn2,
            out + (long)tm1 * HW * 64,
            mode);
        if (mode != 1) { float* tmp = hp1; hp1 = hn1; hn1 = tmp; }
        if (mode != 0) { float* tmp = hp2; hp2 = hn2; hn2 = tmp; }
    }
}